// Round 3
// baseline (137.965 us; speedup 1.0000x reference)
//
#include <hip/hip_runtime.h>
#include <hip/hip_bf16.h>
#include <cstdint>

#define DEVI __device__ __forceinline__

typedef __bf16 bf16x8 __attribute__((ext_vector_type(8)));
typedef float  f32x4  __attribute__((ext_vector_type(4)));

constexpr int Hdim = 1024;
constexpr int Vdim = 32000;
constexpr int Ldim = 512;
constexpr int Bdim = 256;

DEVI unsigned short f2bf(float f) {
  __bf16 h = (__bf16)f;                       // RNE
  return __builtin_bit_cast(unsigned short, h);
}

DEVI void load_lds16(const void* g, void* l) {
  __builtin_amdgcn_global_load_lds(
      (const __attribute__((address_space(1))) unsigned int*)g,
      (__attribute__((address_space(3))) unsigned int*)l, 16, 0, 0);
}

// ===========================================================================
// gemm_flat: C[256 x 32000] = A[256x1024](bf16) @ W[32000x1024](f32)^T + bias
// Counted-vmcnt deep pipeline (T3/T4):
//   - W tile (64 rows x 32 k, fp32, 8 KB) staged by global_load_lds into 4
//     LDS buffers, prefetch distance 3 (~900cy = HBM latency).
//     Slot-XOR swizzle (slot ^= row&7) applied on SOURCE addr (DMA writes
//     linearly) and on the read side -> conflict-free ds_read_b128.
//   - A fragments direct from L2 to registers, 4 static reg sets, dist 3.
//   - per step: s_waitcnt vmcnt(12) (never 0) -> barrier -> issue group i+3
//     -> ds_read W + cvt to bf16 + 16 MFMA. Tail uses dummy re-issues of the
//     last tile so vmcnt(12) stays uniform.
//   - epilogue: bias add, store C, per-block row {max,sum} partials (plse).
// MFMA 16x16x32_bf16; C/D: col=lane&15, row=(lane>>4)*4+reg (m89-verified).
// ===========================================================================
constexpr int GF_NKT = 32;            // 1024 / 32

__global__ __launch_bounds__(256, 2)
void gemm_flat(const unsigned short* __restrict__ A,
               const float* __restrict__ W,
               const float* __restrict__ bias,
               float* __restrict__ C,
               float2* __restrict__ plse)
{
  __shared__ float lW[4][64 * 32];    // 4 bufs x 8 KB

  const int t    = threadIdx.x;
  const int lane = t & 63;
  const int wv   = t >> 6;
  const int r16  = lane & 15;
  const int k8   = (lane >> 4) * 8;
  const int s0   = (lane >> 4) * 2;   // 16B-slot index of frag start
  const int n0   = blockIdx.x * 64;
  const int drow0 = wv * 16 + (lane >> 3);   // DMA row (q=0)

  uint4 aset[4][4];
  f32x4 acc[4][4];
#pragma unroll
  for (int m = 0; m < 4; ++m)
#pragma unroll
    for (int n = 0; n < 4; ++n)
#pragma unroll
      for (int r = 0; r < 4; ++r) acc[m][n][r] = 0.f;

#define ISSUE_A(SET, KT) do {                                                  \
    const int ko_ = (KT) * 32 + k8;                                            \
    _Pragma("unroll")                                                          \
    for (int m = 0; m < 4; ++m)                                                \
      aset[SET][m] = *reinterpret_cast<const uint4*>(                          \
          A + (size_t)(wv * 64 + m * 16 + r16) * 1024 + ko_);                  \
  } while (0)

#define ISSUE_W(BUF, KT) do {                                                  \
    _Pragma("unroll")                                                          \
    for (int q = 0; q < 2; ++q) {                                              \
      const int row_ = drow0 + q * 8;                                          \
      const float* src_ = W + (size_t)(n0 + row_) * 1024 + (KT) * 32           \
                          + (((lane & 7) ^ (row_ & 7)) * 4);                   \
      load_lds16(src_, &lW[BUF][(wv * 2 + q) * 256]);                          \
    }                                                                          \
  } while (0)

#define STEP_COMPUTE(P) do {                                                   \
    bf16x8 bw[4];                                                              \
    _Pragma("unroll")                                                          \
    for (int n = 0; n < 4; ++n) {                                              \
      const int row_ = n * 16 + r16;                                           \
      const int sw_  = row_ & 7;                                               \
      f32x4 w0 = *reinterpret_cast<const f32x4*>(                              \
          &lW[P][row_ * 32 + ((s0 ^ sw_) * 4)]);                               \
      f32x4 w1 = *reinterpret_cast<const f32x4*>(                              \
          &lW[P][row_ * 32 + (((s0 + 1) ^ sw_) * 4)]);                         \
      bf16x8 v;                                                                \
      v[0] = (__bf16)w0[0]; v[1] = (__bf16)w0[1];                              \
      v[2] = (__bf16)w0[2]; v[3] = (__bf16)w0[3];                              \
      v[4] = (__bf16)w1[0]; v[5] = (__bf16)w1[1];                              \
      v[6] = (__bf16)w1[2]; v[7] = (__bf16)w1[3];                              \
      bw[n] = v;                                                               \
    }                                                                          \
    _Pragma("unroll")                                                          \
    for (int m = 0; m < 4; ++m) {                                              \
      bf16x8 am = __builtin_bit_cast(bf16x8, aset[P][m]);                      \
      _Pragma("unroll")                                                        \
      for (int n = 0; n < 4; ++n)                                              \
        acc[m][n] = __builtin_amdgcn_mfma_f32_16x16x32_bf16(am, bw[n],         \
                                                            acc[m][n], 0,0,0);\
    }                                                                          \
  } while (0)

#define STEP(P, I) do {                                                        \
    asm volatile("s_waitcnt vmcnt(12)" ::: "memory");                          \
    __builtin_amdgcn_sched_barrier(0);                                         \
    __builtin_amdgcn_s_barrier();                                              \
    __builtin_amdgcn_sched_barrier(0);                                         \
    { const int kn_ = ((I) + 3 < GF_NKT) ? (I) + 3 : GF_NKT - 1;               \
      ISSUE_A((P + 3) & 3, kn_); ISSUE_W((P + 3) & 3, kn_); }                  \
    __builtin_amdgcn_sched_barrier(0);                                         \
    STEP_COMPUTE(P);                                                           \
    __builtin_amdgcn_sched_barrier(0);                                         \
  } while (0)

  // prologue: groups 0,1,2 (A -> set k, W -> buf k)
  ISSUE_A(0, 0); ISSUE_W(0, 0);
  ISSUE_A(1, 1); ISSUE_W(1, 1);
  ISSUE_A(2, 2); ISSUE_W(2, 2);

  for (int ib = 0; ib < GF_NKT; ib += 4) {
    STEP(0, ib);
    STEP(1, ib + 1);
    STEP(2, ib + 2);
    STEP(3, ib + 3);
  }

#undef STEP
#undef STEP_COMPUTE
#undef ISSUE_W
#undef ISSUE_A

  // ---------------- epilogue: bias, store, LSE partials ----------------
#pragma unroll
  for (int n = 0; n < 4; ++n) {
    const int col = n0 + n * 16 + r16;
    const float bv = bias[col];
#pragma unroll
    for (int m = 0; m < 4; ++m) {
      const int rbase = wv * 64 + m * 16 + (lane >> 4) * 4;
#pragma unroll
      for (int r = 0; r < 4; ++r) {
        const float v = acc[m][n][r] + bv;
        acc[m][n][r] = v;
        C[(size_t)(rbase + r) * Vdim + col] = v;
      }
    }
  }
#pragma unroll
  for (int m = 0; m < 4; ++m) {
#pragma unroll
    for (int r = 0; r < 4; ++r) {
      float mx = fmaxf(fmaxf(acc[m][0][r], acc[m][1][r]),
                       fmaxf(acc[m][2][r], acc[m][3][r]));
#pragma unroll
      for (int o = 1; o < 16; o <<= 1) mx = fmaxf(mx, __shfl_xor(mx, o, 16));
      float s = 0.f;
#pragma unroll
      for (int n = 0; n < 4; ++n) s += __expf(acc[m][n][r] - mx);
#pragma unroll
      for (int o = 1; o < 16; o <<= 1) s += __shfl_xor(s, o, 16);
      if (r16 == 0) {
        const int row = wv * 64 + m * 16 + (lane >> 4) * 4 + r;
        plse[(size_t)row * gridDim.x + blockIdx.x] = make_float2(mx, s);
      }
    }
  }
}

// ---------------------------------------------------------------------------
// Small-GEMM engine (unchanged from round 2): reg-staged dbuf, split-K atomics
// ---------------------------------------------------------------------------
template<int WM, bool ABF16, bool DUAL>
__global__ __launch_bounds__(256, 2)
void gemm_bt(const void* __restrict__ Av0, const float* __restrict__ Wt0,
             const void* __restrict__ Av1, const float* __restrict__ Wt1,
             const float* __restrict__ bias,
             float* __restrict__ C0, float* __restrict__ C1,
             int K, int ldc, int col_off, int act, int aact0,
             int nsplit)
{
  constexpr int MT    = 4 * WM;
  constexpr int PITCH = 40;
  constexpr int ITA   = MT / 32;
  constexpr int MR    = WM / 16;

  __shared__ unsigned short lA[2 * MT * PITCH];
  __shared__ unsigned short lW[2 * 64 * PITCH];

  const int t  = threadIdx.x;
  const int m0 = blockIdx.y * MT;
  const int n0 = blockIdx.x * 64;

  int kz = blockIdx.z, half = 0;
  if (DUAL) { half = (kz >= nsplit) ? 1 : 0; kz -= half * nsplit; }
  const int NK = K / (32 * nsplit);
  const int kb = kz * NK;

  const void*  Av = (DUAL && half) ? Av1 : Av0;
  const float* Wt = (DUAL && half) ? Wt1 : Wt0;
  float*       C  = (DUAL && half) ? C1  : C0;
  const int  aact = (DUAL && half) ? 0 : aact0;

  const int tr = t >> 3;
  const int tc = (t & 7) * 4;

  const float*          Af = ABF16 ? nullptr : ((const float*)Av) + (size_t)m0 * K;
  const unsigned short* Ab = ABF16 ? ((const unsigned short*)Av) + (size_t)m0 * K : nullptr;
  const float*          Wb = Wt + (size_t)n0 * K;

  const int lane = t & 63;
  const int wv   = t >> 6;
  const int r16  = lane & 15;
  const int k8   = (lane >> 4) * 8;

  f32x4 acc[MR][4];
#pragma unroll
  for (int m = 0; m < MR; ++m)
#pragma unroll
    for (int n = 0; n < 4; ++n)
#pragma unroll
      for (int r = 0; r < 4; ++r) acc[m][n][r] = 0.f;

  struct RS { f32x4 ra[ITA]; ushort4 rab[ITA]; f32x4 rw[2]; };

  auto loadT = [&](RS& rg, int kt) {
    const int ko = (kb + kt) * 32 + tc;
    if constexpr (ABF16) {
      const unsigned short* ap = Ab + ko;
#pragma unroll
      for (int i = 0; i < ITA; ++i)
        rg.rab[i] = *reinterpret_cast<const ushort4*>(ap + (size_t)(tr + 32 * i) * K);
    } else {
      const float* ap = Af + ko;
#pragma unroll
      for (int i = 0; i < ITA; ++i)
        rg.ra[i] = *reinterpret_cast<const f32x4*>(ap + (size_t)(tr + 32 * i) * K);
    }
    const float* wp = Wb + ko;
#pragma unroll
    for (int i = 0; i < 2; ++i)
      rg.rw[i] = *reinterpret_cast<const f32x4*>(wp + (size_t)(tr + 32 * i) * K);
  };

  auto storeT = [&](RS& rg, int bo) {
    unsigned short* sA = &lA[bo * MT * PITCH];
    unsigned short* sW = &lW[bo * 64 * PITCH];
#pragma unroll
    for (int i = 0; i < ITA; ++i) {
      ushort4 u;
      if constexpr (ABF16) u = rg.rab[i];
      else {
        f32x4 v = rg.ra[i];
        if (aact) { v[0]=fmaxf(v[0],0.f); v[1]=fmaxf(v[1],0.f);
                    v[2]=fmaxf(v[2],0.f); v[3]=fmaxf(v[3],0.f); }
        u.x = f2bf(v[0]); u.y = f2bf(v[1]); u.z = f2bf(v[2]); u.w = f2bf(v[3]);
      }
      *reinterpret_cast<ushort4*>(&sA[(tr + 32 * i) * PITCH + tc]) = u;
    }
#pragma unroll
    for (int i = 0; i < 2; ++i) {
      f32x4 v = rg.rw[i]; ushort4 u;
      u.x = f2bf(v[0]); u.y = f2bf(v[1]); u.z = f2bf(v[2]); u.w = f2bf(v[3]);
      *reinterpret_cast<ushort4*>(&sW[(tr + 32 * i) * PITCH + tc]) = u;
    }
  };

  auto comp = [&](int bo) {
    const unsigned short* sA = &lA[bo * MT * PITCH];
    const unsigned short* sW = &lW[bo * 64 * PITCH];
    bf16x8 af[MR], bfr[4];
#pragma unroll
    for (int m = 0; m < MR; ++m)
      af[m] = *reinterpret_cast<const bf16x8*>(&sA[(wv * WM + m * 16 + r16) * PITCH + k8]);
#pragma unroll
    for (int n = 0; n < 4; ++n)
      bfr[n] = *reinterpret_cast<const bf16x8*>(&sW[(n * 16 + r16) * PITCH + k8]);
#pragma unroll
    for (int m = 0; m < MR; ++m)
#pragma unroll
      for (int n = 0; n < 4; ++n)
        acc[m][n] = __builtin_amdgcn_mfma_f32_16x16x32_bf16(af[m], bfr[n], acc[m][n], 0, 0, 0);
  };

#define GB_BARRIER() do { \
    asm volatile("s_waitcnt lgkmcnt(0)" ::: "memory"); \
    __builtin_amdgcn_sched_barrier(0); \
    __builtin_amdgcn_s_barrier(); \
  } while (0)

  RS ra_, rb_;
  loadT(ra_, 0);
  loadT(rb_, 1);
  storeT(ra_, 0);
  GB_BARRIER();

  for (int kt = 0; kt < NK; kt += 2) {
    if (kt + 2 < NK) loadT(ra_, kt + 2);
    comp(0);
    storeT(rb_, 1);
    GB_BARRIER();
    if (kt + 3 < NK) loadT(rb_, kt + 3);
    comp(1);
    if (kt + 2 < NK) {
      storeT(ra_, 0);
      GB_BARRIER();
    }
  }
#undef GB_BARRIER

#pragma unroll
  for (int n = 0; n < 4; ++n) {
    const int col = n0 + n * 16 + r16;
    const float bv = (bias && nsplit == 1) ? bias[col] : 0.f;
#pragma unroll
    for (int m = 0; m < MR; ++m) {
      const int rbase = m0 + wv * WM + m * 16 + (lane >> 4) * 4;
#pragma unroll
      for (int r = 0; r < 4; ++r) {
        float v = acc[m][n][r] + bv;
        if (act) v = fmaxf(v, 0.f);
        if (nsplit > 1) {
          atomicAdd(&C[(size_t)(rbase + r) * ldc + col_off + col], v);
        } else {
          C[(size_t)(rbase + r) * ldc + col_off + col] = v;
        }
      }
    }
  }
}

// ---- prep: X0=[emb|h], X1=[emb|0]; bias-init alog/xact/gi/gh ---------------
__global__ void prep_kernel(const int* __restrict__ ids, const float* __restrict__ hid,
                            const float* __restrict__ emb,
                            const float* __restrict__ attn_b, const float* __restrict__ comb_b,
                            const float* __restrict__ b_ih, const float* __restrict__ b_hh,
                            float* __restrict__ X0, float* __restrict__ X1,
                            float* __restrict__ alog, float* __restrict__ xact,
                            float* __restrict__ gi, float* __restrict__ gh)
{
  const int b = blockIdx.x, t = threadIdx.x;
  const int row = ids[b];
  f32x4 e = *reinterpret_cast<const f32x4*>(emb + (size_t)row * Hdim + t * 4);
  *reinterpret_cast<f32x4*>(X0 + (size_t)b * 2048 + t * 4) = e;
  *reinterpret_cast<f32x4*>(X1 + (size_t)b * 2048 + t * 4) = e;
  f32x4 h = *reinterpret_cast<const f32x4*>(hid + (size_t)b * Hdim + t * 4);
  *reinterpret_cast<f32x4*>(X0 + (size_t)b * 2048 + 1024 + t * 4) = h;
  f32x4 z4 = {0.f, 0.f, 0.f, 0.f};
  *reinterpret_cast<f32x4*>(X1 + (size_t)b * 2048 + 1024 + t * 4) = z4;
  if (t < 128)
    *reinterpret_cast<f32x4*>(alog + (size_t)b * Ldim + t * 4) =
        *reinterpret_cast<const f32x4*>(attn_b + t * 4);
  *reinterpret_cast<f32x4*>(xact + (size_t)b * Hdim + t * 4) =
      *reinterpret_cast<const f32x4*>(comb_b + t * 4);
#pragma unroll
  for (int i = 0; i < 3; ++i) {
    *reinterpret_cast<f32x4*>(gi + (size_t)b * 3072 + i * 1024 + t * 4) =
        *reinterpret_cast<const f32x4*>(b_ih + i * 1024 + t * 4);
    *reinterpret_cast<f32x4*>(gh + (size_t)b * 3072 + i * 1024 + t * 4) =
        *reinterpret_cast<const f32x4*>(b_hh + i * 1024 + t * 4);
  }
}

// ---- encoder transpose: encT[h][l] = enc[l][h] -----------------------------
__global__ void transpose_kernel(const float* __restrict__ enc, float* __restrict__ encT)
{
  __shared__ float tile[64][65];
  const int l0 = blockIdx.x * 64, h0 = blockIdx.y * 64;
  const int t = threadIdx.x;
  const int c = t & 63, rr = t >> 6;
#pragma unroll
  for (int p = 0; p < 16; ++p) {
    const int r = p * 4 + rr;
    tile[r][c] = enc[(size_t)(l0 + r) * Hdim + h0 + c];
  }
  __syncthreads();
#pragma unroll
  for (int p = 0; p < 16; ++p) {
    const int r = p * 4 + rr;
    encT[(size_t)(h0 + r) * Ldim + l0 + c] = tile[c][r];
  }
}

// ---- softmax over L=512 per row --------------------------------------------
__global__ void attn_softmax_kernel(const float* __restrict__ logits, float* __restrict__ wout)
{
  __shared__ float red[256];
  const int b = blockIdx.x, t = threadIdx.x;
  const float x0 = logits[b * Ldim + t];
  const float x1 = logits[b * Ldim + 256 + t];
  red[t] = fmaxf(x0, x1); __syncthreads();
  for (int o = 128; o > 0; o >>= 1) { if (t < o) red[t] = fmaxf(red[t], red[t + o]); __syncthreads(); }
  const float m = red[0]; __syncthreads();
  const float e0 = __expf(x0 - m), e1 = __expf(x1 - m);
  red[t] = e0 + e1; __syncthreads();
  for (int o = 128; o > 0; o >>= 1) { if (t < o) red[t] += red[t + o]; __syncthreads(); }
  const float inv = 1.f / red[0];
  wout[b * Ldim + t]       = e0 * inv;
  wout[b * Ldim + 256 + t] = e1 * inv;
}

// ---- GRU pointwise ---------------------------------------------------------
DEVI float sigm(float x) { return 1.f / (1.f + __expf(-x)); }

__global__ void gru_kernel(const float* __restrict__ gi, const float* __restrict__ gh,
                           const float* __restrict__ hin,
                           float* __restrict__ hnew, unsigned short* __restrict__ hnbf)
{
  const int idx = blockIdx.x * 256 + threadIdx.x;
  const int b = idx >> 10, j = idx & 1023;
  const float* gib = gi + (size_t)b * 3072;
  const float* ghb = gh + (size_t)b * 3072;
  const float r = sigm(gib[j] + ghb[j]);
  const float z = sigm(gib[1024 + j] + ghb[1024 + j]);
  const float n = tanhf(gib[2048 + j] + r * ghb[2048 + j]);
  const float h = hin[idx];
  const float hn = (1.f - z) * n + z * h;
  hnew[idx] = hn;
  hnbf[idx] = f2bf(hn);
}

// ---- LSE: reduce per-block partials to lse[b] ------------------------------
__global__ void lse_reduce(const float2* __restrict__ part, int npart,
                           float* __restrict__ lse)
{
  __shared__ float rm[256], rs[256];
  const int b = blockIdx.x, t = threadIdx.x;
  float m = -1e30f, s = 0.f;
  for (int j = t; j < npart; j += 256) {
    const float2 p = part[(size_t)b * npart + j];
    const float nm = fmaxf(m, p.x);
    s = s * __expf(m - nm) + p.y * __expf(p.x - nm);
    m = nm;
  }
  rm[t] = m; rs[t] = s; __syncthreads();
  for (int o = 128; o > 0; o >>= 1) {
    if (t < o) {
      const float m2 = rm[t + o], s2 = rs[t + o];
      const float nm = fmaxf(rm[t], m2);
      rs[t] = rs[t] * __expf(rm[t] - nm) + s2 * __expf(m2 - nm);
      rm[t] = nm;
    }
    __syncthreads();
  }
  if (t == 0) lse[b] = rm[0] + __logf(rs[0]);
}

// ---- subtract lse in place (2048 blocks, full-BW streaming) ----------------
__global__ void lsm_sub(const float* __restrict__ lse, float* __restrict__ out)
{
  const int b = blockIdx.x >> 3, c = blockIdx.x & 7;
  const float l = lse[b];
  f32x4* row4 = reinterpret_cast<f32x4*>(out + (size_t)b * Vdim) + c * 1000;
  for (int i = threadIdx.x; i < 1000; i += 256) {
    f32x4 x = row4[i];
    x[0] -= l; x[1] -= l; x[2] -= l; x[3] -= l;
    row4[i] = x;
  }
}

// ---------------------------------------------------------------------------
extern "C" void kernel_launch(void* const* d_in, const int* in_sizes, int n_in,
                              void* d_out, int out_size, void* d_ws, size_t ws_size,
                              hipStream_t stream)
{
  (void)in_sizes; (void)n_in; (void)out_size; (void)ws_size;

  const int*   ids    = (const int*)  d_in[0];
  const float* hid    = (const float*)d_in[1];
  const float* enc    = (const float*)d_in[2];
  const float* emb    = (const float*)d_in[3];
  const float* attn_W = (const float*)d_in[4];
  const float* attn_b = (const float*)d_in[5];
  const float* comb_W = (const float*)d_in[6];
  const float* comb_b = (const float*)d_in[7];
  const float* W_ih   = (const float*)d_in[8];
  const float* W_hh   = (const float*)d_in[9];
  const float* b_ih   = (const float*)d_in[10];
  const float* b_hh   = (const float*)d_in[11];
  const float* out_W  = (const float*)d_in[12];
  const float* out_b  = (const float*)d_in[13];

  float* out_logits = (float*)d_out;                       // [B,V]
  float* out_h      = out_logits + (size_t)Bdim * Vdim;    // [B,H]
  float* out_attw   = out_h + (size_t)Bdim * Hdim;         // [B,L]

  char* w = (char*)d_ws;
  float* X0   = (float*)w; w += (size_t)Bdim * 2048 * 4;
  float* X1   = (float*)w; w += (size_t)Bdim * 2048 * 4;
  float* encT = (float*)w; w += (size_t)Hdim * Ldim * 4;
  float* alog = (float*)w; w += (size_t)Bdim * Ldim * 4;
  float* xact = (float*)w; w += (size_t)Bdim * Hdim * 4;
  float* gi   = (float*)w; w += (size_t)Bdim * 3 * Hdim * 4;
  float* gh   = (float*)w; w += (size_t)Bdim * 3 * Hdim * 4;
  unsigned short* hnbf = (unsigned short*)w; w += (size_t)Bdim * Hdim * 2;
  float2* plse = (float2*)w; w += (size_t)Bdim * (Vdim / 64) * 8;
  float* lse  = (float*)w; w += (size_t)Bdim * 4;

  prep_kernel<<<Bdim, 256, 0, stream>>>(ids, hid, emb, attn_b, comb_b, b_ih, b_hh,
                                        X0, X1, alog, xact, gi, gh);
  transpose_kernel<<<dim3(Ldim / 64, Hdim / 64), 256, 0, stream>>>(enc, encT);

  // attn logits [B,L] += X0 @ attn_W^T   (split-K=8, bias pre-init)
  gemm_bt<32, false, false><<<dim3(Ldim / 64, 2, 8), 256, 0, stream>>>(
      X0, attn_W, nullptr, nullptr, nullptr, alog, nullptr,
      2048, Ldim, 0, 0, 0, 8);
  attn_softmax_kernel<<<Bdim, 256, 0, stream>>>(alog, out_attw);

  // attn_applied [B,H] += attn_w @ encT^T -> X1 right half (split-K=4)
  gemm_bt<32, false, false><<<dim3(Hdim / 64, 2, 4), 256, 0, stream>>>(
      out_attw, encT, nullptr, nullptr, nullptr, X1, nullptr,
      512, 2048, 1024, 0, 0, 4);

  // xact [B,H] += X1 @ comb_W^T  (split-K=8; ReLU deferred to gi's A-staging)
  gemm_bt<32, false, false><<<dim3(Hdim / 64, 2, 8), 256, 0, stream>>>(
      X1, comb_W, nullptr, nullptr, nullptr, xact, nullptr,
      2048, Hdim, 0, 0, 0, 8);

  // gi += relu(xact) @ W_ih^T ; gh += h @ W_hh^T  (dual, split-K=4)
  gemm_bt<32, false, true><<<dim3(3 * Hdim / 64, 2, 8), 256, 0, stream>>>(
      xact, W_ih, hid, W_hh, nullptr, gi, gh,
      1024, 3 * Hdim, 0, 0, 1, 4);

  gru_kernel<<<Bdim * Hdim / 256, 256, 0, stream>>>(gi, gh, hid, out_h, hnbf);

  // logits [B,V] = h_new @ out_W^T + out_b  (deep-pipelined flat GEMM)
  gemm_flat<<<Vdim / 64, 256, 0, stream>>>(hnbf, out_W, out_b, out_logits, plse);

  lse_reduce<<<Bdim, 256, 0, stream>>>(plse, Vdim / 64, lse);
  lsm_sub<<<Bdim * 8, 256, 0, stream>>>(lse, out_logits);
}